// Round 2
// baseline (735.220 us; speedup 1.0000x reference)
//
#include <hip/hip_runtime.h>
#include <stdint.h>

#define NG   64
#define NPG  4096
#define HD   256
#define NC0  256
#define NC1  64
#define KSPLIT 2

typedef __attribute__((ext_vector_type(8))) short bfx8;   // 8 bf16 (4 VGPRs)
typedef __attribute__((ext_vector_type(4))) float fx4;    // MFMA acc

__device__ __forceinline__ unsigned short f2bf(float f) {
  union { float f; unsigned int u; } v; v.f = f;
  return (unsigned short)((v.u + 0x7FFFu + ((v.u >> 16) & 1u)) >> 16);  // RNE
}
__device__ __forceinline__ unsigned int pack2(float a, float b) {
  return (unsigned int)f2bf(a) | ((unsigned int)f2bf(b) << 16);
}

// async global->LDS, 16B per lane; LDS dest = wave-uniform base + lane*16
#define ASYNC_COPY16(gptr, lptr) \
  __builtin_amdgcn_global_load_lds((const __attribute__((address_space(1))) unsigned int*)(gptr), \
                                   (__attribute__((address_space(3))) unsigned int*)(lptr), 16, 0, 0)

// ---------------- W0 -> W0F: MFMA B-fragment order, bf16 (unchanged) ----------------
__global__ __launch_bounds__(256) void k_w0f(const float* __restrict__ W0,
                                             unsigned short* __restrict__ W0F) {
  int gid = blockIdx.x * 256 + threadIdx.x;   // 8192 granules
  int l15 = gid & 15;
  int q   = (gid >> 4) & 3;
  int ks  = (gid >> 6) & 1;
  int kc  = (gid >> 7) & 3;
  int cblk = gid >> 9;
  int c = cblk * 16 + l15;
  int kb = kc * 64 + ks * 32 + q * 8;
  unsigned int u[4];
  #pragma unroll
  for (int j = 0; j < 8; j += 2)
    u[j >> 1] = pack2(W0[(size_t)(kb + j) * 256 + c], W0[(size_t)(kb + j + 1) * 256 + c]);
  *(float4*)(W0F + (size_t)gid * 8) = *(float4*)u;
}

// ---------------- K1: softmax(x@W0+b0) -> A0T (bf16 [c][node]); also emits xT ----------------
// 512 thr (8 waves), 128-node x 256-cluster tile, BK=64 dbuf.
//  - All xT/A0T stores are 256 B-per-row, LANE-CONTIGUOUS per instruction (fixes the
//    +135 MB write amplification measured with 128 B row spans in the previous version).
//  - XOR granule swizzle slot = g ^ ((row^(row>>4))&7) on the x tile: stage writes,
//    A-frag b128 reads, and emit u16 column reads all <=4-way.
//  - W0F B-fragments explicitly double-buffered (load group g+1 during group g MFMAs);
//    launch_bounds(512,4) gives the VGPR headroom (cap 128) the old 64-VGPR alloc lacked.
__global__ __launch_bounds__(512, 4) void k_assign0(
    const float* __restrict__ x, const unsigned short* __restrict__ W0F,
    const float* __restrict__ b0, unsigned short* __restrict__ A0T,
    unsigned short* __restrict__ xT, int g0) {
  __shared__ unsigned short lds_u[18432];   // xs: [2][128][64] (32 KB) | at: [128][144] (36864 B)
  __shared__ float red[512];

  int gl = blockIdx.x >> 5, nt = blockIdx.x & 31;
  int tid = threadIdx.x;
  int wave = tid >> 6, lane = tid & 63;
  int wm = wave >> 2, wn = wave & 3;
  int l15 = lane & 15, q = lane >> 4;

  fx4 acc[4][4];
  #pragma unroll
  for (int i = 0; i < 4; ++i)
    #pragma unroll
    for (int j = 0; j < 4; ++j) acc[i][j] = fx4{0.f, 0.f, 0.f, 0.f};

  const float* xbase = x + ((size_t)(g0 + gl) * NPG + (size_t)nt * 128) * HD;
  int snode = tid >> 2;                      // 0..127 (staging row)
  int sseg  = (tid & 3) * 16;                // float offset within 64-chunk
  int sg0   = (tid & 3) * 2;                 // even granule index
  int ssw   = (snode ^ (snode >> 4)) & 7;    // stage swizzle

  bfx8 bvc[4], bvn[4];
  #pragma unroll
  for (int ni = 0; ni < 4; ++ni)             // B-frag group 0
    bvc[ni] = *(const bfx8*)(W0F + ((size_t)(((wn * 4 + ni) * 8 + 0) * 64 + lane)) * 8);

  // prologue: stage chunk 0 into buf 0
  {
    const float4* src = (const float4*)(xbase + (size_t)snode * HD + sseg);
    float4 v0 = src[0], v1 = src[1], v2 = src[2], v3 = src[3];
    float4 pv[2]; unsigned int* pu = (unsigned int*)pv;
    pu[0] = pack2(v0.x, v0.y); pu[1] = pack2(v0.z, v0.w);
    pu[2] = pack2(v1.x, v1.y); pu[3] = pack2(v1.z, v1.w);
    pu[4] = pack2(v2.x, v2.y); pu[5] = pack2(v2.z, v2.w);
    pu[6] = pack2(v3.x, v3.y); pu[7] = pack2(v3.z, v3.w);
    unsigned short* drow = &lds_u[snode << 6];
    *(float4*)(drow + (((sg0    ) ^ ssw) << 3)) = pv[0];
    *(float4*)(drow + (((sg0 + 1) ^ ssw) << 3)) = pv[1];
  }
  __syncthreads();

  #pragma unroll
  for (int kc = 0; kc < 4; ++kc) {
    const unsigned short* xb = &lds_u[(kc & 1) * 8192];
    float4 v0, v1, v2, v3;
    if (kc < 3) {   // issue next-chunk global loads EARLY (hide HBM under mfma+emit)
      const float4* src = (const float4*)(xbase + (size_t)snode * HD + (kc + 1) * 64 + sseg);
      v0 = src[0]; v1 = src[1]; v2 = src[2]; v3 = src[3];
    }
    #pragma unroll
    for (int ks = 0; ks < 2; ++ks) {
      int g8 = kc * 2 + ks;
      if (g8 < 7) {   // prefetch next B-frag group (L2) under this group's MFMAs
        #pragma unroll
        for (int ni = 0; ni < 4; ++ni)
          bvn[ni] = *(const bfx8*)(W0F + ((size_t)(((wn * 4 + ni) * 8 + g8 + 1) * 64 + lane)) * 8);
      }
      bfx8 af[4];
      #pragma unroll
      for (int mi = 0; mi < 4; ++mi) {
        int row = wm * 64 + mi * 16 + l15;
        int slot = (ks * 4 + q) ^ ((row ^ (row >> 4)) & 7);
        af[mi] = *(const bfx8*)&xb[(row << 6) + (slot << 3)];
      }
      #pragma unroll
      for (int ni = 0; ni < 4; ++ni)
        #pragma unroll
        for (int mi = 0; mi < 4; ++mi)
          acc[mi][ni] = __builtin_amdgcn_mfma_f32_16x16x32_bf16(af[mi], bvc[ni], acc[mi][ni], 0, 0, 0);
      if (g8 < 7) {
        #pragma unroll
        for (int ni = 0; ni < 4; ++ni) bvc[ni] = bvn[ni];
      }
    }
    // emit xT[h][node]: per instruction 4 rows x 256 B lane-contiguous (full lines)
    #pragma unroll
    for (int p2 = 0; p2 < 2; ++p2) {
      int hl = p2 * 32 + wave * 4 + (lane >> 4);   // 0..63 within chunk
      int g = hl >> 3, off = hl & 7;
      int nb = (lane & 15) * 8;                    // node base
      unsigned int u[4];
      #pragma unroll
      for (int j = 0; j < 8; j += 2) {
        int n0 = nb + j, n1 = n0 + 1;
        unsigned short a = xb[(n0 << 6) + ((g ^ ((n0 ^ (n0 >> 4)) & 7)) << 3) + off];
        unsigned short b = xb[(n1 << 6) + ((g ^ ((n1 ^ (n1 >> 4)) & 7)) << 3) + off];
        u[j >> 1] = (unsigned int)a | ((unsigned int)b << 16);
      }
      *(float4*)(xT + ((size_t)gl * HD + kc * 64 + hl) * NPG + (size_t)nt * 128 + nb) = *(float4*)u;
    }
    if (kc < 3) {   // write-late half of the x prefetch
      float4 pv[2]; unsigned int* pu = (unsigned int*)pv;
      pu[0] = pack2(v0.x, v0.y); pu[1] = pack2(v0.z, v0.w);
      pu[2] = pack2(v1.x, v1.y); pu[3] = pack2(v1.z, v1.w);
      pu[4] = pack2(v2.x, v2.y); pu[5] = pack2(v2.z, v2.w);
      pu[6] = pack2(v3.x, v3.y); pu[7] = pack2(v3.z, v3.w);
      unsigned short* drow = &lds_u[(((kc & 1) ^ 1) * 8192) + (snode << 6)];
      *(float4*)(drow + (((sg0    ) ^ ssw) << 3)) = pv[0];
      *(float4*)(drow + (((sg0 + 1) ^ ssw) << 3)) = pv[1];
    }
    __syncthreads();
  }

  // ---- epilogue: bias + softmax over 256 clusters per node-row ----
  float bv4[4];
  #pragma unroll
  for (int ni = 0; ni < 4; ++ni) bv4[ni] = b0[wn * 64 + ni * 16 + l15];
  #pragma unroll
  for (int mi = 0; mi < 4; ++mi)
    #pragma unroll
    for (int ni = 0; ni < 4; ++ni)
      #pragma unroll
      for (int r = 0; r < 4; ++r) acc[mi][ni][r] += bv4[ni];

  float mrow[4][4];
  #pragma unroll
  for (int mi = 0; mi < 4; ++mi)
    #pragma unroll
    for (int r = 0; r < 4; ++r) {
      float m = fmaxf(fmaxf(acc[mi][0][r], acc[mi][1][r]), fmaxf(acc[mi][2][r], acc[mi][3][r]));
      #pragma unroll
      for (int off = 1; off < 16; off <<= 1) m = fmaxf(m, __shfl_xor(m, off));
      mrow[mi][r] = m;
    }
  if (l15 == 0) {
    #pragma unroll
    for (int mi = 0; mi < 4; ++mi)
      #pragma unroll
      for (int r = 0; r < 4; ++r)
        red[(wm * 64 + mi * 16 + q * 4 + r) * 4 + wn] = mrow[mi][r];
  }
  __syncthreads();
  #pragma unroll
  for (int mi = 0; mi < 4; ++mi)
    #pragma unroll
    for (int r = 0; r < 4; ++r) {
      float4 rv = *(const float4*)&red[(wm * 64 + mi * 16 + q * 4 + r) * 4];
      mrow[mi][r] = fmaxf(fmaxf(rv.x, rv.y), fmaxf(rv.z, rv.w));
    }
  __syncthreads();
  float srow[4][4];
  #pragma unroll
  for (int mi = 0; mi < 4; ++mi)
    #pragma unroll
    for (int r = 0; r < 4; ++r) {
      float s = 0.f;
      #pragma unroll
      for (int ni = 0; ni < 4; ++ni) {
        float e = __expf(acc[mi][ni][r] - mrow[mi][r]);
        acc[mi][ni][r] = e; s += e;
      }
      #pragma unroll
      for (int off = 1; off < 16; off <<= 1) s += __shfl_xor(s, off);
      srow[mi][r] = s;
    }
  if (l15 == 0) {
    #pragma unroll
    for (int mi = 0; mi < 4; ++mi)
      #pragma unroll
      for (int r = 0; r < 4; ++r)
        red[(wm * 64 + mi * 16 + q * 4 + r) * 4 + wn] = srow[mi][r];
  }
  __syncthreads();
  #pragma unroll
  for (int mi = 0; mi < 4; ++mi)
    #pragma unroll
    for (int r = 0; r < 4; ++r) {
      float4 rv = *(const float4*)&red[(wm * 64 + mi * 16 + q * 4 + r) * 4];
      float inv = 1.f / (rv.x + rv.y + rv.z + rv.w);
      #pragma unroll
      for (int ni = 0; ni < 4; ++ni) acc[mi][ni][r] *= inv;
    }
  __syncthreads();   // xs dead; reuse as 'at'

  // ---- transposed store: A0T[gl][c][node], two 128-cluster phases via LDS ----
  unsigned short* at = lds_u;                 // [128 c][144 n]
  unsigned short* A0Tg = A0T + (size_t)gl * NC0 * NPG + (size_t)nt * 128;
  #pragma unroll
  for (int p = 0; p < 2; ++p) {
    if ((wn >> 1) == p) {
      int cb = (wn & 1) * 64;
      #pragma unroll
      for (int mi = 0; mi < 4; ++mi) {
        int ncol = wm * 64 + mi * 16 + q * 4;
        #pragma unroll
        for (int ni = 0; ni < 4; ++ni) {
          int cl = cb + ni * 16 + l15;
          uint2 w;
          w.x = pack2(acc[mi][ni][0], acc[mi][ni][1]);
          w.y = pack2(acc[mi][ni][2], acc[mi][ni][3]);
          *(uint2*)(at + cl * 144 + ncol) = w;
        }
      }
    }
    __syncthreads();
    #pragma unroll
    for (int rp = 0; rp < 4; ++rp) {          // 4 rows x 256 B lane-contiguous per instr
      int row = rp * 32 + wave * 4 + (lane >> 4);
      int nb = (lane & 15) * 8;
      bfx8 vv = *(const bfx8*)(at + row * 144 + nb);
      *(bfx8*)(A0Tg + (size_t)(p * 128 + row) * NPG + nb) = vv;
    }
    __syncthreads();
  }
}

// ---------------- K2: f0p[kidx][g][c][h] = A0T[g][c][:] . xT[g][h][:] (unchanged) ----------------
__global__ __launch_bounds__(256, 2) void k_pool0(
    const unsigned short* __restrict__ A0T, const unsigned short* __restrict__ xT,
    float* __restrict__ f0p, int g0) {
  __shared__ unsigned short a_s[128 * 64];
  __shared__ unsigned short b_s[128 * 64];
  int bid = blockIdx.x;
  int kidx = bid & 1;
  int nt = (bid >> 1) & 1;
  int mt = (bid >> 2) & 1;
  int gl = bid >> 3;

  int tid = threadIdx.x;
  int wave = tid >> 6, lane = tid & 63;
  int wm = wave >> 1, wnn = wave & 1;
  int l15 = lane & 15, q = lane >> 4;

  const int KPER = NPG / KSPLIT;   // 2048
  const unsigned short* abase = A0T + ((size_t)gl * NC0 + (size_t)mt * 128) * NPG + (size_t)kidx * KPER;
  const unsigned short* bbase = xT  + ((size_t)gl * HD  + (size_t)nt * 128) * NPG + (size_t)kidx * KPER;

  fx4 acc[4][4];
  #pragma unroll
  for (int i = 0; i < 4; ++i)
    #pragma unroll
    for (int j = 0; j < 4; ++j) acc[i][j] = fx4{0.f, 0.f, 0.f, 0.f};

  int srow = lane >> 3;                 // 0..7 row within 8-row group
  int sg   = (lane & 7) ^ srow;         // swizzled 16B granule
  size_t soff = (size_t)srow * NPG + (size_t)sg * 8;   // shorts

  for (int k0 = 0; k0 < KPER; k0 += 64) {
    #pragma unroll
    for (int i = 0; i < 4; ++i) {
      int r0 = wave * 32 + i * 8;
      ASYNC_COPY16(abase + (size_t)r0 * NPG + k0 + soff, &a_s[r0 * 64]);
      ASYNC_COPY16(bbase + (size_t)r0 * NPG + k0 + soff, &b_s[r0 * 64]);
    }
    __syncthreads();
    #pragma unroll
    for (int ks = 0; ks < 2; ++ks) {
      int gx = ((ks * 4 + q) ^ (l15 & 7)) << 3;   // swizzled granule offset (shorts)
      bfx8 af[4], bf[4];
      #pragma unroll
      for (int mi = 0; mi < 4; ++mi)
        af[mi] = *(const bfx8*)&a_s[(wm * 64 + mi * 16 + l15) * 64 + gx];
      #pragma unroll
      for (int ni = 0; ni < 4; ++ni)
        bf[ni] = *(const bfx8*)&b_s[(wnn * 64 + ni * 16 + l15) * 64 + gx];
      #pragma unroll
      for (int ni = 0; ni < 4; ++ni)
        #pragma unroll
        for (int mi = 0; mi < 4; ++mi)
          acc[mi][ni] = __builtin_amdgcn_mfma_f32_16x16x32_bf16(af[mi], bf[ni], acc[mi][ni], 0, 0, 0);
    }
    __syncthreads();
  }

  float* dst = f0p + (size_t)kidx * NG * NC0 * HD
             + ((size_t)(g0 + gl) * NC0 + (size_t)mt * 128) * HD + (size_t)nt * 128;
  #pragma unroll
  for (int mi = 0; mi < 4; ++mi)
    #pragma unroll
    for (int ni = 0; ni < 4; ++ni) {
      int c = wm * 64 + mi * 16 + q * 4;
      int h = wnn * 64 + ni * 16 + l15;
      #pragma unroll
      for (int r = 0; r < 4; ++r)
        dst[(size_t)(c + r) * HD + h] = acc[mi][ni][r];
    }
}

// ---------------- f0 = f0p0 + f0p1 (in place: f0 == f0p0) ----------------
__global__ __launch_bounds__(256) void k_f0sum(float* __restrict__ f0) {
  size_t i = ((size_t)blockIdx.x * 256 + threadIdx.x) * 4;
  float4 a = *(const float4*)(f0 + i);
  float4 b = *(const float4*)(f0 + (size_t)NG * NC0 * HD + i);
  a.x += b.x; a.y += b.y; a.z += b.z; a.w += b.w;
  *(float4*)(f0 + i) = a;
}

// ---------------- K3: A1 = softmax(f0 @ W1 + b1); W1 staged in LDS (unchanged) ----------------
__global__ __launch_bounds__(256) void k_assign1(
    const float* __restrict__ f0, const float* __restrict__ W1,
    const float* __restrict__ b1, float* __restrict__ A1) {
  __shared__ float w1s[256 * 64];   // 64 KB
  int tid = threadIdx.x;
  #pragma unroll
  for (int i = 0; i < 16; ++i) {
    int off = i * 1024 + tid * 4;
    *(float4*)(w1s + off) = *(const float4*)(W1 + off);
  }
  __syncthreads();
  int lane = tid & 63;
  int rbase = blockIdx.x * 32 + (tid >> 6) * 8;
  float bias = b1[lane];
  for (int rr = 0; rr < 8; ++rr) {
    int row = rbase + rr;
    const float* fr = f0 + (size_t)row * 256;
    float acc = bias;
    for (int k = 0; k < 256; k += 4) {
      float4 fv = *(const float4*)(fr + k);
      acc += fv.x * w1s[(k    ) * 64 + lane];
      acc += fv.y * w1s[(k + 1) * 64 + lane];
      acc += fv.z * w1s[(k + 2) * 64 + lane];
      acc += fv.w * w1s[(k + 3) * 64 + lane];
    }
    float m = acc;
    #pragma unroll
    for (int off = 1; off < 64; off <<= 1) m = fmaxf(m, __shfl_xor(m, off));
    float e = __expf(acc - m);
    float s = e;
    #pragma unroll
    for (int off = 1; off < 64; off <<= 1) s += __shfl_xor(s, off);
    A1[(size_t)row * 64 + lane] = e / s;
  }
}

// ---------------- K4: f1[b][c*256+h] = sum_c0 A1[b][c0][c] * f0[b][c0][h] (unchanged) ----------------
__global__ __launch_bounds__(256) void k_pool1(
    const float* __restrict__ A1, const float* __restrict__ f0, float* __restrict__ f1) {
  int b = blockIdx.x >> 2, cg = blockIdx.x & 3;
  int h = threadIdx.x;
  const float* a1p = A1 + (size_t)b * NC0 * NC1 + cg * 16;
  const float* f0p = f0 + (size_t)b * NC0 * HD + h;
  float acc[16];
  #pragma unroll
  for (int j = 0; j < 16; ++j) acc[j] = 0.f;
  for (int c0 = 0; c0 < 256; ++c0) {
    float fv = f0p[(size_t)c0 * 256];
    #pragma unroll
    for (int j = 0; j < 16; ++j) acc[j] += a1p[c0 * 64 + j] * fv;
  }
  float* d = f1 + (size_t)b * 16384 + (size_t)(cg * 16) * 256 + h;
  #pragma unroll
  for (int j = 0; j < 16; ++j) d[(size_t)j * 256] = acc[j];
}

// ---------------- K5a: ot[b][h] += f1[b][ks*256..+256] . Wf[ks*256..][h] (unchanged) ----------------
__global__ __launch_bounds__(512) void k_final_partial(
    const float* __restrict__ f1, const float* __restrict__ Wf, float* __restrict__ ot) {
  __shared__ float f1s[64 * 256];   // 64 KB: f1[all b][k-slice]
  int ht = blockIdx.x & 3;          // h-tile 0..3
  int ks = blockIdx.x >> 2;         // k-slice 0..63
  int tid = threadIdx.x;
  {
    int b = tid >> 3, c0 = (tid & 7) * 4;
    const float* s = f1 + (size_t)b * 16384 + (size_t)ks * 256 + c0;
    float* d = f1s + b * 256 + c0;
    #pragma unroll
    for (int i = 0; i < 8; ++i) *(float4*)(d + i * 32) = *(const float4*)(s + i * 32);
  }
  __syncthreads();
  int h = ht * 64 + (tid & 63);
  int b0 = (tid >> 6) * 8;          // wave's 8 graphs
  const float* wp = Wf + (size_t)ks * 256 * 256 + h;
  float acc[8];
  #pragma unroll
  for (int j = 0; j < 8; ++j) acc[j] = 0.f;
  for (int k = 0; k < 256; k += 4) {
    float w0 = wp[(size_t)(k    ) * 256];
    float w1 = wp[(size_t)(k + 1) * 256];
    float w2 = wp[(size_t)(k + 2) * 256];
    float w3 = wp[(size_t)(k + 3) * 256];
    #pragma unroll
    for (int j = 0; j < 8; ++j) {
      float4 fv = *(const float4*)(f1s + (b0 + j) * 256 + k);
      acc[j] += fv.x * w0 + fv.y * w1 + fv.z * w2 + fv.w * w3;
    }
  }
  #pragma unroll
  for (int j = 0; j < 8; ++j) atomicAdd(&ot[(b0 + j) * 256 + h], acc[j]);
}

// ---------------- K5b: out = relu(ot + bf) (unchanged) ----------------
__global__ __launch_bounds__(256) void k_final_out(
    const float* __restrict__ ot, const float* __restrict__ bfv, float* __restrict__ out) {
  int i = blockIdx.x * 256 + threadIdx.x;
  float v = ot[i] + bfv[i & 255];
  out[i] = v > 0.f ? v : 0.f;
}

extern "C" void kernel_launch(void* const* d_in, const int* in_sizes, int n_in,
                              void* d_out, int out_size, void* d_ws, size_t ws_size,
                              hipStream_t stream) {
  const float* x   = (const float*)d_in[0];
  const float* W0  = (const float*)d_in[3];
  const float* b0  = (const float*)d_in[4];
  const float* W1  = (const float*)d_in[5];
  const float* b1  = (const float*)d_in[6];
  const float* Wf  = (const float*)d_in[7];
  const float* bfv = (const float*)d_in[8];
  float* out = (float*)d_out;
  char* ws = (char*)d_ws;

  // layout: f0p [2x16 MB) @0 (partial0 doubles as final f0); ot @32M; W0F @32M+64K;
  // chunk region @32M+192K: xT (G*2MB) + A0T (G*2MB). f1 aliases xT, A1 aliases A0T.
  float* f0p = (float*)ws;
  float* f0  = f0p;
  float* ot  = (float*)(ws + ((size_t)32 << 20));
  unsigned short* W0F = (unsigned short*)(ws + ((size_t)32 << 20) + 65536);
  size_t chunk_off = ((size_t)32 << 20) + 65536 + 131072;
  size_t per_graph = (size_t)4 * HD * NPG;   // xT(2MB)+A0T(2MB)
  size_t avail = ws_size > chunk_off ? ws_size - chunk_off : 0;
  int G = (int)(avail / per_graph);
  if (G > 64) G = 64;
  if (G < 1) G = 1;
  unsigned short* xT  = (unsigned short*)(ws + chunk_off);
  unsigned short* A0T = xT + (size_t)G * HD * NPG;
  float* f1 = (float*)xT;    // 16 MB, used after k_pool0 (needs G>=8; ws floor gives G=64)
  float* A1 = (float*)A0T;   // 4 MB, used after k_pool0

  hipMemsetAsync(ot, 0, 65536, stream);
  k_w0f<<<32, 256, 0, stream>>>(W0, W0F);

  for (int g0 = 0; g0 < NG; g0 += G) {
    int gc = (NG - g0 < G) ? (NG - g0) : G;
    k_assign0<<<gc * 32, 512, 0, stream>>>(x, W0F, b0, A0T, xT, g0);
    k_pool0<<<gc * 4 * KSPLIT, 256, 0, stream>>>(A0T, xT, f0p, g0);
  }
  k_f0sum<<<4096, 256, 0, stream>>>(f0);
  k_assign1<<<512, 256, 0, stream>>>(f0, W1, b1, A1);
  k_pool1<<<256, 256, 0, stream>>>(A1, f0, f1);
  k_final_partial<<<256, 512, 0, stream>>>(f1, Wf, ot);
  k_final_out<<<64, 256, 0, stream>>>(ot, bfv, out);
}

// Round 3
// 690.662 us; speedup vs baseline: 1.0645x; 1.0645x over previous
//
#include <hip/hip_runtime.h>
#include <stdint.h>

#define NG   64
#define NPG  4096
#define HD   256
#define NC0  256
#define NC1  64

typedef __attribute__((ext_vector_type(8))) short bfx8;   // 8 bf16 (4 VGPRs)
typedef __attribute__((ext_vector_type(4))) float fx4;    // MFMA acc

__device__ __forceinline__ unsigned short f2bf(float f) {
  union { float f; unsigned int u; } v; v.f = f;
  return (unsigned short)((v.u + 0x7FFFu + ((v.u >> 16) & 1u)) >> 16);  // RNE
}
__device__ __forceinline__ unsigned int pack2(float a, float b) {
  return (unsigned int)f2bf(a) | ((unsigned int)f2bf(b) << 16);
}

// async global->LDS, 16B per lane; LDS dest = wave-uniform base + lane*16
#define ASYNC_COPY16(gptr, lptr) \
  __builtin_amdgcn_global_load_lds((const __attribute__((address_space(1))) unsigned int*)(gptr), \
                                   (__attribute__((address_space(3))) unsigned int*)(lptr), 16, 0, 0)

// ---------------- W0 -> W0F: MFMA B-fragment order, bf16 (unchanged) ----------------
__global__ __launch_bounds__(256) void k_w0f(const float* __restrict__ W0,
                                             unsigned short* __restrict__ W0F) {
  int gid = blockIdx.x * 256 + threadIdx.x;   // 8192 granules
  int l15 = gid & 15;
  int q   = (gid >> 4) & 3;
  int ks  = (gid >> 6) & 1;
  int kc  = (gid >> 7) & 3;
  int cblk = gid >> 9;
  int c = cblk * 16 + l15;
  int kb = kc * 64 + ks * 32 + q * 8;
  unsigned int u[4];
  #pragma unroll
  for (int j = 0; j < 8; j += 2)
    u[j >> 1] = pack2(W0[(size_t)(kb + j) * 256 + c], W0[(size_t)(kb + j + 1) * 256 + c]);
  *(float4*)(W0F + (size_t)gid * 8) = *(float4*)u;
}

// ---------------- K1: softmax(x@W0+b0) -> A0T (bf16 [c][node]); also emits xT ----------------
// Round-0 structure (proven 247us / 262MB writes) + T14 load-early/write-late split +
// W0F B-fragment double-buffer. __launch_bounds__(512,2): 192 arch-VGPR headroom
// (64 AGPRs acc count against the unified file) -- the (512,4)/(256,4) variants spilled
// to scratch (+390MB HBM traffic, measured). Occupancy 1 block/CU; latency hidden by ILP.
#define XSP 72
__global__ __launch_bounds__(512, 2) void k_assign0(
    const float* __restrict__ x, const unsigned short* __restrict__ W0F,
    const float* __restrict__ b0, unsigned short* __restrict__ A0T,
    unsigned short* __restrict__ xT, int g0) {
  __shared__ unsigned short xs[2][128 * XSP];   // 2 x 18432 B
  __shared__ float red[128 * 4];
  unsigned short* at = (unsigned short*)xs;     // epilogue alias [128 c][136 n] = 34816 B

  int gl = blockIdx.x >> 5, nt = blockIdx.x & 31;
  int tid = threadIdx.x;
  int wave = tid >> 6, lane = tid & 63;
  int wm = wave >> 2, wn = wave & 3;
  int l15 = lane & 15, q = lane >> 4;

  fx4 acc[4][4];
  #pragma unroll
  for (int i = 0; i < 4; ++i)
    #pragma unroll
    for (int j = 0; j < 4; ++j) acc[i][j] = fx4{0.f, 0.f, 0.f, 0.f};

  const float* xbase = x + ((size_t)(g0 + gl) * NPG + (size_t)nt * 128) * HD;
  int snode = tid >> 2, sseg = (tid & 3) * 16;   // 128 rows x 4 segs of 16 floats

  bfx8 bvc[4], bvn[4];
  #pragma unroll
  for (int ni = 0; ni < 4; ++ni)                 // B-frag group 0
    bvc[ni] = *(const bfx8*)(W0F + ((size_t)(((wn * 4 + ni) * 8 + 0) * 64 + lane)) * 8);

  // stage chunk 0 into buf 0
  {
    const float4* src = (const float4*)(xbase + (size_t)snode * HD + sseg);
    float4 v0 = src[0], v1 = src[1], v2 = src[2], v3 = src[3];
    float4 pv[2]; unsigned int* pu = (unsigned int*)pv;
    pu[0] = pack2(v0.x, v0.y); pu[1] = pack2(v0.z, v0.w);
    pu[2] = pack2(v1.x, v1.y); pu[3] = pack2(v1.z, v1.w);
    pu[4] = pack2(v2.x, v2.y); pu[5] = pack2(v2.z, v2.w);
    pu[6] = pack2(v3.x, v3.y); pu[7] = pack2(v3.z, v3.w);
    float4* d = (float4*)&xs[0][snode * XSP + sseg];
    d[0] = pv[0]; d[1] = pv[1];
  }
  __syncthreads();

  for (int kc = 0; kc < 4; ++kc) {
    int buf = kc & 1;
    float4 v0, v1, v2, v3;
    if (kc < 3) {   // T14: issue next-chunk global loads EARLY
      const float4* src = (const float4*)(xbase + (size_t)snode * HD + (kc + 1) * 64 + sseg);
      v0 = src[0]; v1 = src[1]; v2 = src[2]; v3 = src[3];
    }
    // MFMA on buf; B fragments double-buffered from L2-resident W0F
    #pragma unroll
    for (int ks = 0; ks < 2; ++ks) {
      int g8 = kc * 2 + ks;
      if (g8 < 7) {
        #pragma unroll
        for (int ni = 0; ni < 4; ++ni)
          bvn[ni] = *(const bfx8*)(W0F + ((size_t)(((wn * 4 + ni) * 8 + g8 + 1) * 64 + lane)) * 8);
      }
      int kk = ks * 32 + q * 8;
      bfx8 af[4];
      #pragma unroll
      for (int mi = 0; mi < 4; ++mi)
        af[mi] = *(const bfx8*)&xs[buf][(wm * 64 + mi * 16 + l15) * XSP + kk];
      #pragma unroll
      for (int ni = 0; ni < 4; ++ni)
        #pragma unroll
        for (int mi = 0; mi < 4; ++mi)
          acc[mi][ni] = __builtin_amdgcn_mfma_f32_16x16x32_bf16(af[mi], bvc[ni], acc[mi][ni], 0, 0, 0);
      if (g8 < 7) {
        #pragma unroll
        for (int ni = 0; ni < 4; ++ni) bvc[ni] = bvn[ni];
      }
    }
    // emit xT[h][node] for this k-chunk from LDS (fused transpose)
    {
      int hl = tid >> 3;             // 0..63
      int seg = (tid & 7) * 16;      // node segment
      unsigned int u[8];
      #pragma unroll
      for (int i = 0; i < 16; i += 2) {
        unsigned short a = xs[buf][(seg + i) * XSP + hl];
        unsigned short b = xs[buf][(seg + i + 1) * XSP + hl];
        u[i >> 1] = (unsigned int)a | ((unsigned int)b << 16);
      }
      float4* dst = (float4*)(xT + ((size_t)gl * HD + kc * 64 + hl) * NPG + (size_t)nt * 128 + seg);
      dst[0] = *(float4*)&u[0];
      dst[1] = *(float4*)&u[4];
    }
    if (kc < 3) {   // T14: pack + LDS-write LATE
      float4 pv[2]; unsigned int* pu = (unsigned int*)pv;
      pu[0] = pack2(v0.x, v0.y); pu[1] = pack2(v0.z, v0.w);
      pu[2] = pack2(v1.x, v1.y); pu[3] = pack2(v1.z, v1.w);
      pu[4] = pack2(v2.x, v2.y); pu[5] = pack2(v2.z, v2.w);
      pu[6] = pack2(v3.x, v3.y); pu[7] = pack2(v3.z, v3.w);
      float4* d = (float4*)&xs[buf ^ 1][snode * XSP + sseg];
      d[0] = pv[0]; d[1] = pv[1];
    }
    __syncthreads();
  }

  // ---- epilogue: bias + softmax over 256 clusters per node-row ----
  float bv4[4];
  #pragma unroll
  for (int ni = 0; ni < 4; ++ni) bv4[ni] = b0[wn * 64 + ni * 16 + l15];
  #pragma unroll
  for (int mi = 0; mi < 4; ++mi)
    #pragma unroll
    for (int ni = 0; ni < 4; ++ni)
      #pragma unroll
      for (int r = 0; r < 4; ++r) acc[mi][ni][r] += bv4[ni];

  float mrow[4][4];
  #pragma unroll
  for (int mi = 0; mi < 4; ++mi)
    #pragma unroll
    for (int r = 0; r < 4; ++r) {
      float m = fmaxf(fmaxf(acc[mi][0][r], acc[mi][1][r]), fmaxf(acc[mi][2][r], acc[mi][3][r]));
      #pragma unroll
      for (int off = 1; off < 16; off <<= 1) m = fmaxf(m, __shfl_xor(m, off));
      mrow[mi][r] = m;
    }
  if (l15 == 0) {
    #pragma unroll
    for (int mi = 0; mi < 4; ++mi)
      #pragma unroll
      for (int r = 0; r < 4; ++r)
        red[(wm * 64 + mi * 16 + q * 4 + r) * 4 + wn] = mrow[mi][r];
  }
  __syncthreads();
  #pragma unroll
  for (int mi = 0; mi < 4; ++mi)
    #pragma unroll
    for (int r = 0; r < 4; ++r) {
      float4 rv = *(const float4*)&red[(wm * 64 + mi * 16 + q * 4 + r) * 4];
      mrow[mi][r] = fmaxf(fmaxf(rv.x, rv.y), fmaxf(rv.z, rv.w));
    }
  __syncthreads();
  float srow[4][4];
  #pragma unroll
  for (int mi = 0; mi < 4; ++mi)
    #pragma unroll
    for (int r = 0; r < 4; ++r) {
      float s = 0.f;
      #pragma unroll
      for (int ni = 0; ni < 4; ++ni) {
        float e = __expf(acc[mi][ni][r] - mrow[mi][r]);
        acc[mi][ni][r] = e; s += e;
      }
      #pragma unroll
      for (int off = 1; off < 16; off <<= 1) s += __shfl_xor(s, off);
      srow[mi][r] = s;
    }
  if (l15 == 0) {
    #pragma unroll
    for (int mi = 0; mi < 4; ++mi)
      #pragma unroll
      for (int r = 0; r < 4; ++r)
        red[(wm * 64 + mi * 16 + q * 4 + r) * 4 + wn] = srow[mi][r];
  }
  __syncthreads();
  #pragma unroll
  for (int mi = 0; mi < 4; ++mi)
    #pragma unroll
    for (int r = 0; r < 4; ++r) {
      float4 rv = *(const float4*)&red[(wm * 64 + mi * 16 + q * 4 + r) * 4];
      float inv = 1.f / (rv.x + rv.y + rv.z + rv.w);
      #pragma unroll
      for (int ni = 0; ni < 4; ++ni) acc[mi][ni][r] *= inv;
    }
  __syncthreads();   // xs dead; reuse as 'at'

  // ---- transposed store: A0T[gl][c][node], two 128-cluster phases via LDS ----
  unsigned short* A0Tg = A0T + (size_t)gl * NC0 * NPG + (size_t)nt * 128;
  #pragma unroll
  for (int p = 0; p < 2; ++p) {
    if ((wn >> 1) == p) {
      int cb = (wn & 1) * 64;
      #pragma unroll
      for (int mi = 0; mi < 4; ++mi) {
        int ncol = wm * 64 + mi * 16 + q * 4;
        #pragma unroll
        for (int ni = 0; ni < 4; ++ni) {
          int cl = cb + ni * 16 + l15;
          uint2 w;
          w.x = pack2(acc[mi][ni][0], acc[mi][ni][1]);
          w.y = pack2(acc[mi][ni][2], acc[mi][ni][3]);
          *(uint2*)(at + cl * 136 + ncol) = w;
        }
      }
    }
    __syncthreads();
    {
      int row = tid >> 2, seg = (tid & 3) * 32;
      const float4* s4 = (const float4*)(at + row * 136 + seg);
      float4 a = s4[0], b = s4[1], c = s4[2], d = s4[3];
      float4* d4 = (float4*)(A0Tg + (size_t)(p * 128 + row) * NPG + seg);
      d4[0] = a; d4[1] = b; d4[2] = c; d4[3] = d;
    }
    __syncthreads();
  }
}

// ---------------- K2: f0[g][c][h] = A0T[g][c][:] . xT[g][h][:], full K, direct write ----------------
// KSPLIT removed (no f0p partials, no k_f0sum). 2-phase pipeline: dbuf LDS, next chunk's
// global_load_lds issued before current chunk's MFMAs, one barrier/iter. 512 thr, 128x128
// tile, wave-tile 64x32 (32 AGPR). Grid = G*4.
__global__ __launch_bounds__(512, 2) void k_pool0(
    const unsigned short* __restrict__ A0T, const unsigned short* __restrict__ xT,
    float* __restrict__ f0, int g0) {
  __shared__ unsigned short a_s[2][128 * 64];
  __shared__ unsigned short b_s[2][128 * 64];
  int bid = blockIdx.x;
  int nt = bid & 1;
  int mt = (bid >> 1) & 1;
  int gl = bid >> 2;

  int tid = threadIdx.x;
  int wave = tid >> 6, lane = tid & 63;
  int wm = wave >> 2, wn = wave & 3;
  int l15 = lane & 15, q = lane >> 4;

  const unsigned short* abase = A0T + ((size_t)gl * NC0 + (size_t)mt * 128) * NPG;
  const unsigned short* bbase = xT  + ((size_t)gl * HD  + (size_t)nt * 128) * NPG;

  fx4 acc[4][2];
  #pragma unroll
  for (int i = 0; i < 4; ++i)
    #pragma unroll
    for (int j = 0; j < 2; ++j) acc[i][j] = fx4{0.f, 0.f, 0.f, 0.f};

  int srow = lane >> 3;                 // 0..7 row within 8-row group
  int sg   = (lane & 7) ^ srow;         // swizzled 16B granule
  size_t soff = (size_t)srow * NPG + (size_t)sg * 8;   // shorts

  // prologue: stage chunk 0 into buf 0 (wave w stages rows w*16..+15 of both arrays)
  #pragma unroll
  for (int i = 0; i < 2; ++i) {
    int r0 = wave * 16 + i * 8;
    ASYNC_COPY16(abase + (size_t)r0 * NPG + soff, &a_s[0][r0 * 64]);
    ASYNC_COPY16(bbase + (size_t)r0 * NPG + soff, &b_s[0][r0 * 64]);
  }
  __syncthreads();

  for (int t = 0; t < NPG / 64; ++t) {
    int buf = t & 1;
    if (t < NPG / 64 - 1) {   // issue next chunk into other buffer; drains at the barrier below
      int k0 = (t + 1) * 64;
      #pragma unroll
      for (int i = 0; i < 2; ++i) {
        int r0 = wave * 16 + i * 8;
        ASYNC_COPY16(abase + (size_t)r0 * NPG + k0 + soff, &a_s[buf ^ 1][r0 * 64]);
        ASYNC_COPY16(bbase + (size_t)r0 * NPG + k0 + soff, &b_s[buf ^ 1][r0 * 64]);
      }
    }
    #pragma unroll
    for (int ks = 0; ks < 2; ++ks) {
      int gx = ((ks * 4 + q) ^ (l15 & 7)) << 3;   // swizzled granule offset (shorts)
      bfx8 af[4], bf[2];
      #pragma unroll
      for (int mi = 0; mi < 4; ++mi)
        af[mi] = *(const bfx8*)&a_s[buf][(wm * 64 + mi * 16 + l15) * 64 + gx];
      #pragma unroll
      for (int ni = 0; ni < 2; ++ni)
        bf[ni] = *(const bfx8*)&b_s[buf][(wn * 32 + ni * 16 + l15) * 64 + gx];
      #pragma unroll
      for (int ni = 0; ni < 2; ++ni)
        #pragma unroll
        for (int mi = 0; mi < 4; ++mi)
          acc[mi][ni] = __builtin_amdgcn_mfma_f32_16x16x32_bf16(af[mi], bf[ni], acc[mi][ni], 0, 0, 0);
    }
    __syncthreads();
  }

  float* dst = f0 + ((size_t)(g0 + gl) * NC0 + (size_t)mt * 128) * HD + (size_t)nt * 128;
  #pragma unroll
  for (int mi = 0; mi < 4; ++mi)
    #pragma unroll
    for (int ni = 0; ni < 2; ++ni) {
      int c = wm * 64 + mi * 16 + q * 4;
      int h = wn * 32 + ni * 16 + l15;
      #pragma unroll
      for (int r = 0; r < 4; ++r)
        dst[(size_t)(c + r) * HD + h] = acc[mi][ni][r];
    }
}

// ---------------- K3: A1 = softmax(f0 @ W1 + b1); W1 staged in LDS (unchanged) ----------------
__global__ __launch_bounds__(256) void k_assign1(
    const float* __restrict__ f0, const float* __restrict__ W1,
    const float* __restrict__ b1, float* __restrict__ A1) {
  __shared__ float w1s[256 * 64];   // 64 KB
  int tid = threadIdx.x;
  #pragma unroll
  for (int i = 0; i < 16; ++i) {
    int off = i * 1024 + tid * 4;
    *(float4*)(w1s + off) = *(const float4*)(W1 + off);
  }
  __syncthreads();
  int lane = tid & 63;
  int rbase = blockIdx.x * 32 + (tid >> 6) * 8;
  float bias = b1[lane];
  for (int rr = 0; rr < 8; ++rr) {
    int row = rbase + rr;
    const float* fr = f0 + (size_t)row * 256;
    float acc = bias;
    for (int k = 0; k < 256; k += 4) {
      float4 fv = *(const float4*)(fr + k);
      acc += fv.x * w1s[(k    ) * 64 + lane];
      acc += fv.y * w1s[(k + 1) * 64 + lane];
      acc += fv.z * w1s[(k + 2) * 64 + lane];
      acc += fv.w * w1s[(k + 3) * 64 + lane];
    }
    float m = acc;
    #pragma unroll
    for (int off = 1; off < 64; off <<= 1) m = fmaxf(m, __shfl_xor(m, off));
    float e = __expf(acc - m);
    float s = e;
    #pragma unroll
    for (int off = 1; off < 64; off <<= 1) s += __shfl_xor(s, off);
    A1[(size_t)row * 64 + lane] = e / s;
  }
}

// ---------------- K4: f1[b][c*256+h] = sum_c0 A1[b][c0][c] * f0[b][c0][h] (unchanged) ----------------
__global__ __launch_bounds__(256) void k_pool1(
    const float* __restrict__ A1, const float* __restrict__ f0, float* __restrict__ f1) {
  int b = blockIdx.x >> 2, cg = blockIdx.x & 3;
  int h = threadIdx.x;
  const float* a1p = A1 + (size_t)b * NC0 * NC1 + cg * 16;
  const float* f0p = f0 + (size_t)b * NC0 * HD + h;
  float acc[16];
  #pragma unroll
  for (int j = 0; j < 16; ++j) acc[j] = 0.f;
  for (int c0 = 0; c0 < 256; ++c0) {
    float fv = f0p[(size_t)c0 * 256];
    #pragma unroll
    for (int j = 0; j < 16; ++j) acc[j] += a1p[c0 * 64 + j] * fv;
  }
  float* d = f1 + (size_t)b * 16384 + (size_t)(cg * 16) * 256 + h;
  #pragma unroll
  for (int j = 0; j < 16; ++j) d[(size_t)j * 256] = acc[j];
}

// ---------------- K5a: ot[b][h] += f1[b][ks*256..+256] . Wf[ks*256..][h] (unchanged) ----------------
__global__ __launch_bounds__(512) void k_final_partial(
    const float* __restrict__ f1, const float* __restrict__ Wf, float* __restrict__ ot) {
  __shared__ float f1s[64 * 256];   // 64 KB: f1[all b][k-slice]
  int ht = blockIdx.x & 3;          // h-tile 0..3
  int ks = blockIdx.x >> 2;         // k-slice 0..63
  int tid = threadIdx.x;
  {
    int b = tid >> 3, c0 = (tid & 7) * 4;
    const float* s = f1 + (size_t)b * 16384 + (size_t)ks * 256 + c0;
    float* d = f1s + b * 256 + c0;
    #pragma unroll
    for (int i = 0; i < 8; ++i) *(float4*)(d + i * 32) = *(const float4*)(s + i * 32);
  }
  __syncthreads();
  int h = ht * 64 + (tid & 63);
  int b0 = (tid >> 6) * 8;          // wave's 8 graphs
  const float* wp = Wf + (size_t)ks * 256 * 256 + h;
  float acc[8];
  #pragma unroll
  for (int j = 0; j < 8; ++j) acc[j] = 0.f;
  for (int k = 0; k < 256; k += 4) {
    float w0 = wp[(size_t)(k    ) * 256];
    float w1 = wp[(size_t)(k + 1) * 256];
    float w2 = wp[(size_t)(k + 2) * 256];
    float w3 = wp[(size_t)(k + 3) * 256];
    #pragma unroll
    for (int j = 0; j < 8; ++j) {
      float4 fv = *(const float4*)(f1s + (b0 + j) * 256 + k);
      acc[j] += fv.x * w0 + fv.y * w1 + fv.z * w2 + fv.w * w3;
    }
  }
  #pragma unroll
  for (int j = 0; j < 8; ++j) atomicAdd(&ot[(b0 + j) * 256 + h], acc[j]);
}

// ---------------- K5b: out = relu(ot + bf) (unchanged) ----------------
__global__ __launch_bounds__(256) void k_final_out(
    const float* __restrict__ ot, const float* __restrict__ bfv, float* __restrict__ out) {
  int i = blockIdx.x * 256 + threadIdx.x;
  float v = ot[i] + bfv[i & 255];
  out[i] = v > 0.f ? v : 0.f;
}

extern "C" void kernel_launch(void* const* d_in, const int* in_sizes, int n_in,
                              void* d_out, int out_size, void* d_ws, size_t ws_size,
                              hipStream_t stream) {
  const float* x   = (const float*)d_in[0];
  const float* W0  = (const float*)d_in[3];
  const float* b0  = (const float*)d_in[4];
  const float* W1  = (const float*)d_in[5];
  const float* b1  = (const float*)d_in[6];
  const float* Wf  = (const float*)d_in[7];
  const float* bfv = (const float*)d_in[8];
  float* out = (float*)d_out;
  char* ws = (char*)d_ws;

  // layout: f0 16 MB @0; ot @32M; W0F @32M+64K;
  // chunk region @32M+192K: xT (G*2MB) + A0T (G*2MB). f1 aliases xT, A1 aliases A0T.
  float* f0  = (float*)ws;
  float* ot  = (float*)(ws + ((size_t)32 << 20));
  unsigned short* W0F = (unsigned short*)(ws + ((size_t)32 << 20) + 65536);
  size_t chunk_off = ((size_t)32 << 20) + 65536 + 131072;
  size_t per_graph = (size_t)4 * HD * NPG;   // xT(2MB)+A0T(2MB)
  size_t avail = ws_size > chunk_off ? ws_size - chunk_off : 0;
  int G = (int)(avail / per_graph);
  if (G > 64) G = 64;
  if (G < 1) G = 1;
  unsigned short* xT  = (unsigned short*)(ws + chunk_off);
  unsigned short* A0T = xT + (size_t)G * HD * NPG;
  float* f1 = (float*)xT;    // 16 MB, used after k_pool0 (needs G>=8; ws floor gives G=64)
  float* A1 = (float*)A0T;   // 4 MB, used after k_pool0

  hipMemsetAsync(ot, 0, 65536, stream);
  k_w0f<<<32, 256, 0, stream>>>(W0, W0F);

  for (int g0 = 0; g0 < NG; g0 += G) {
    int gc = (NG - g0 < G) ? (NG - g0) : G;
    k_assign0<<<gc * 32, 512, 0, stream>>>(x, W0F, b0, A0T, xT, g0);
    k_pool0<<<gc * 4, 512, 0, stream>>>(A0T, xT, f0, g0);
  }
  k_assign1<<<512, 256, 0, stream>>>(f0, W1, b1, A1);
  k_pool1<<<256, 256, 0, stream>>>(A1, f0, f1);
  k_final_partial<<<256, 512, 0, stream>>>(f1, Wf, ot);
  k_final_out<<<64, 256, 0, stream>>>(ot, bfv, out);
}

// Round 4
// 653.222 us; speedup vs baseline: 1.1255x; 1.0573x over previous
//
#include <hip/hip_runtime.h>
#include <stdint.h>

#define NG   64
#define NPG  4096
#define HD   256
#define NC0  256
#define NC1  64

typedef __attribute__((ext_vector_type(8))) short bfx8;   // 8 bf16 (4 VGPRs)
typedef __attribute__((ext_vector_type(4))) float fx4;    // MFMA acc

__device__ __forceinline__ unsigned short f2bf(float f) {
  union { float f; unsigned int u; } v; v.f = f;
  return (unsigned short)((v.u + 0x7FFFu + ((v.u >> 16) & 1u)) >> 16);  // RNE
}
__device__ __forceinline__ unsigned int pack2(float a, float b) {
  return (unsigned int)f2bf(a) | ((unsigned int)f2bf(b) << 16);
}

// async global->LDS, 16B per lane; LDS dest = wave-uniform base + lane*16
#define ASYNC_COPY16(gptr, lptr) \
  __builtin_amdgcn_global_load_lds((const __attribute__((address_space(1))) unsigned int*)(gptr), \
                                   (__attribute__((address_space(3))) unsigned int*)(lptr), 16, 0, 0)

// ---------------- W0 -> W0F: MFMA B-fragment order, bf16 (unchanged) ----------------
__global__ __launch_bounds__(256) void k_w0f(const float* __restrict__ W0,
                                             unsigned short* __restrict__ W0F) {
  int gid = blockIdx.x * 256 + threadIdx.x;   // 8192 granules
  int l15 = gid & 15;
  int q   = (gid >> 4) & 3;
  int ks  = (gid >> 6) & 1;
  int kc  = (gid >> 7) & 3;
  int cblk = gid >> 9;
  int c = cblk * 16 + l15;
  int kb = kc * 64 + ks * 32 + q * 8;
  unsigned int u[4];
  #pragma unroll
  for (int j = 0; j < 8; j += 2)
    u[j >> 1] = pack2(W0[(size_t)(kb + j) * 256 + c], W0[(size_t)(kb + j + 1) * 256 + c]);
  *(float4*)(W0F + (size_t)gid * 8) = *(float4*)u;
}

// ---------------- K1: softmax(x@W0+b0) -> A0T chunked; also emits xT chunked ----------------
// 64-node x 256-cluster tiles, 256 thr (4 waves). Occupancy route re-taken with both
// round-1 poisons removed:
//  - launch_bounds(256,3): unified cap 170 (body needs ~140 incl. 64 AGPR acc) -> no spill,
//    3 blocks/CU. ((256,4)'s cap 128 forced arch VGPR=64 -> scratch traffic, measured.)
//  - CHUNKED outputs: xT[g][nt][256h][64n], A0T[g][nt][256c][64n] -> each block writes
//    private contiguous 32KB chunks, 128B full-line rows. (Non-chunked 64-node tiles gave
//    128B row spans shared across blocks -> +240MB write amplification, measured.)
//  - XOR granule swizzle on x tile (stage/A-frag/emit consistent, proven in round 1).
//  - T14 load-early/write-late x prefetch + W0F B-frag double-buffer (proven in round 3).
__global__ __launch_bounds__(256, 3) void k_assign0(
    const float* __restrict__ x, const unsigned short* __restrict__ W0F,
    const float* __restrict__ b0, unsigned short* __restrict__ A0T,
    unsigned short* __restrict__ xT, int g0) {
  __shared__ unsigned short lds_u[9216];   // xs: [2][64][64] (16KB) | at: [128][72] (18432B)
  __shared__ float red[64 * 4];

  int gl = blockIdx.x >> 6, nt = blockIdx.x & 63;
  int tid = threadIdx.x;
  int wn = tid >> 6, lane = tid & 63;
  int l15 = lane & 15, q = lane >> 4;

  fx4 acc[4][4];
  #pragma unroll
  for (int i = 0; i < 4; ++i)
    #pragma unroll
    for (int j = 0; j < 4; ++j) acc[i][j] = fx4{0.f, 0.f, 0.f, 0.f};

  const float* xbase = x + ((size_t)(g0 + gl) * NPG + (size_t)nt * 64) * HD;
  int snode = tid >> 2, sseg = (tid & 3) * 16;   // 64 rows x 4 segs of 16 floats
  int sg0  = (tid & 3) * 2;                      // even granule index
  int ssw  = (snode ^ (snode >> 4)) & 7;         // stage swizzle

  bfx8 bvc[4], bvn[4];
  #pragma unroll
  for (int ni = 0; ni < 4; ++ni)                 // B-frag group 0
    bvc[ni] = *(const bfx8*)(W0F + ((size_t)(((wn * 4 + ni) * 8 + 0) * 64 + lane)) * 8);

  // prologue: stage chunk 0 into buf 0
  {
    const float4* src = (const float4*)(xbase + (size_t)snode * HD + sseg);
    float4 v0 = src[0], v1 = src[1], v2 = src[2], v3 = src[3];
    float4 pv[2]; unsigned int* pu = (unsigned int*)pv;
    pu[0] = pack2(v0.x, v0.y); pu[1] = pack2(v0.z, v0.w);
    pu[2] = pack2(v1.x, v1.y); pu[3] = pack2(v1.z, v1.w);
    pu[4] = pack2(v2.x, v2.y); pu[5] = pack2(v2.z, v2.w);
    pu[6] = pack2(v3.x, v3.y); pu[7] = pack2(v3.z, v3.w);
    unsigned short* drow = &lds_u[snode << 6];
    *(float4*)(drow + (((sg0    ) ^ ssw) << 3)) = pv[0];
    *(float4*)(drow + (((sg0 + 1) ^ ssw) << 3)) = pv[1];
  }
  __syncthreads();

  for (int kc = 0; kc < 4; ++kc) {
    const unsigned short* xb = &lds_u[(kc & 1) * 4096];
    float4 v0, v1, v2, v3;
    if (kc < 3) {   // T14: issue next-chunk global loads EARLY
      const float4* src = (const float4*)(xbase + (size_t)snode * HD + (kc + 1) * 64 + sseg);
      v0 = src[0]; v1 = src[1]; v2 = src[2]; v3 = src[3];
    }
    #pragma unroll
    for (int ks = 0; ks < 2; ++ks) {
      int g8 = kc * 2 + ks;
      if (g8 < 7) {   // B-frag double-buffer (L2-resident W0F)
        #pragma unroll
        for (int ni = 0; ni < 4; ++ni)
          bvn[ni] = *(const bfx8*)(W0F + ((size_t)(((wn * 4 + ni) * 8 + g8 + 1) * 64 + lane)) * 8);
      }
      bfx8 af[4];
      #pragma unroll
      for (int mi = 0; mi < 4; ++mi) {
        int row = mi * 16 + l15;
        int slot = (ks * 4 + q) ^ ((row ^ (row >> 4)) & 7);
        af[mi] = *(const bfx8*)&xb[(row << 6) + (slot << 3)];
      }
      #pragma unroll
      for (int ni = 0; ni < 4; ++ni)
        #pragma unroll
        for (int mi = 0; mi < 4; ++mi)
          acc[mi][ni] = __builtin_amdgcn_mfma_f32_16x16x32_bf16(af[mi], bvc[ni], acc[mi][ni], 0, 0, 0);
      if (g8 < 7) {
        #pragma unroll
        for (int ni = 0; ni < 4; ++ni) bvc[ni] = bvn[ni];
      }
    }
    // emit xT chunk rows [kc*64 .. +64): thread -> h-row (kc*64+hl), nodes sgn..+16 (32B)
    {
      int hl = tid >> 2, s4 = tid & 3, sgn = s4 * 16;
      int g = hl >> 3, off = hl & 7;
      unsigned int u[8];
      #pragma unroll
      for (int i = 0; i < 16; i += 2) {
        int n0 = sgn + i, n1 = n0 + 1;
        unsigned short a = xb[(n0 << 6) + ((g ^ ((n0 ^ (n0 >> 4)) & 7)) << 3) + off];
        unsigned short b = xb[(n1 << 6) + ((g ^ ((n1 ^ (n1 >> 4)) & 7)) << 3) + off];
        u[i >> 1] = (unsigned int)a | ((unsigned int)b << 16);
      }
      float4* dst = (float4*)(xT + ((size_t)(gl * 64 + nt) * HD + kc * 64 + hl) * 64 + sgn);
      dst[0] = *(float4*)&u[0];
      dst[1] = *(float4*)&u[4];
    }
    if (kc < 3) {   // T14: pack + LDS-write LATE
      float4 pv[2]; unsigned int* pu = (unsigned int*)pv;
      pu[0] = pack2(v0.x, v0.y); pu[1] = pack2(v0.z, v0.w);
      pu[2] = pack2(v1.x, v1.y); pu[3] = pack2(v1.z, v1.w);
      pu[4] = pack2(v2.x, v2.y); pu[5] = pack2(v2.z, v2.w);
      pu[6] = pack2(v3.x, v3.y); pu[7] = pack2(v3.z, v3.w);
      unsigned short* drow = &lds_u[(((kc & 1) ^ 1) * 4096) + (snode << 6)];
      *(float4*)(drow + (((sg0    ) ^ ssw) << 3)) = pv[0];
      *(float4*)(drow + (((sg0 + 1) ^ ssw) << 3)) = pv[1];
    }
    __syncthreads();
  }

  // ---- epilogue: bias + softmax over 256 clusters per node-row ----
  float bv4[4];
  #pragma unroll
  for (int ni = 0; ni < 4; ++ni) bv4[ni] = b0[wn * 64 + ni * 16 + l15];
  #pragma unroll
  for (int mi = 0; mi < 4; ++mi)
    #pragma unroll
    for (int ni = 0; ni < 4; ++ni)
      #pragma unroll
      for (int r = 0; r < 4; ++r) acc[mi][ni][r] += bv4[ni];

  float mrow[4][4];
  #pragma unroll
  for (int mi = 0; mi < 4; ++mi)
    #pragma unroll
    for (int r = 0; r < 4; ++r) {
      float m = fmaxf(fmaxf(acc[mi][0][r], acc[mi][1][r]), fmaxf(acc[mi][2][r], acc[mi][3][r]));
      #pragma unroll
      for (int off = 1; off < 16; off <<= 1) m = fmaxf(m, __shfl_xor(m, off));
      mrow[mi][r] = m;
    }
  if (l15 == 0) {
    #pragma unroll
    for (int mi = 0; mi < 4; ++mi)
      #pragma unroll
      for (int r = 0; r < 4; ++r)
        red[(mi * 16 + q * 4 + r) * 4 + wn] = mrow[mi][r];
  }
  __syncthreads();
  #pragma unroll
  for (int mi = 0; mi < 4; ++mi)
    #pragma unroll
    for (int r = 0; r < 4; ++r) {
      float4 rv = *(const float4*)&red[(mi * 16 + q * 4 + r) * 4];
      mrow[mi][r] = fmaxf(fmaxf(rv.x, rv.y), fmaxf(rv.z, rv.w));
    }
  __syncthreads();
  float srow[4][4];
  #pragma unroll
  for (int mi = 0; mi < 4; ++mi)
    #pragma unroll
    for (int r = 0; r < 4; ++r) {
      float s = 0.f;
      #pragma unroll
      for (int ni = 0; ni < 4; ++ni) {
        float e = __expf(acc[mi][ni][r] - mrow[mi][r]);
        acc[mi][ni][r] = e; s += e;
      }
      #pragma unroll
      for (int off = 1; off < 16; off <<= 1) s += __shfl_xor(s, off);
      srow[mi][r] = s;
    }
  if (l15 == 0) {
    #pragma unroll
    for (int mi = 0; mi < 4; ++mi)
      #pragma unroll
      for (int r = 0; r < 4; ++r)
        red[(mi * 16 + q * 4 + r) * 4 + wn] = srow[mi][r];
  }
  __syncthreads();
  #pragma unroll
  for (int mi = 0; mi < 4; ++mi)
    #pragma unroll
    for (int r = 0; r < 4; ++r) {
      float4 rv = *(const float4*)&red[(mi * 16 + q * 4 + r) * 4];
      float inv = 1.f / (rv.x + rv.y + rv.z + rv.w);
      #pragma unroll
      for (int ni = 0; ni < 4; ++ni) acc[mi][ni][r] *= inv;
    }
  __syncthreads();   // xs dead; reuse as 'at'

  // ---- transposed store: A0T chunk [256 c][64 n], two 128-cluster phases via LDS ----
  unsigned short* at = lds_u;                 // [128 c][72 n]
  unsigned short* A0Tg = A0T + (size_t)(gl * 64 + nt) * NC0 * 64;
  #pragma unroll
  for (int p = 0; p < 2; ++p) {
    if ((wn >> 1) == p) {
      int cb = (wn & 1) * 64;
      #pragma unroll
      for (int mi = 0; mi < 4; ++mi) {
        int ncol = mi * 16 + q * 4;
        #pragma unroll
        for (int ni = 0; ni < 4; ++ni) {
          int cl = cb + ni * 16 + l15;
          uint2 w;
          w.x = pack2(acc[mi][ni][0], acc[mi][ni][1]);
          w.y = pack2(acc[mi][ni][2], acc[mi][ni][3]);
          *(uint2*)(at + cl * 72 + ncol) = w;
        }
      }
    }
    __syncthreads();
    {
      int row = tid >> 1, sg2 = (tid & 1) * 32;
      const float4* s4p = (const float4*)(at + row * 72 + sg2);
      float4 a = s4p[0], b = s4p[1], c = s4p[2], d = s4p[3];
      float4* d4 = (float4*)(A0Tg + (size_t)(p * 128 + row) * 64 + sg2);
      d4[0] = a; d4[1] = b; d4[2] = c; d4[3] = d;
    }
    __syncthreads();
  }
}

// ---------------- K2: f0[g][c][h] = A0T[g][c][:] . xT[g][h][:] over chunked inputs ----------------
// Same verified 2-phase pipeline; only addressing changed for the chunked layouts:
// k-chunk t == nt-chunk t, rows are 64-short (128B) and each ASYNC group reads a
// contiguous 1KB run (better DRAM locality than the old 8KB-strided rows).
__global__ __launch_bounds__(512, 2) void k_pool0(
    const unsigned short* __restrict__ A0T, const unsigned short* __restrict__ xT,
    float* __restrict__ f0, int g0) {
  __shared__ unsigned short a_s[2][128 * 64];
  __shared__ unsigned short b_s[2][128 * 64];
  int bid = blockIdx.x;
  int nt = bid & 1;
  int mt = (bid >> 1) & 1;
  int gl = bid >> 2;

  int tid = threadIdx.x;
  int wave = tid >> 6, lane = tid & 63;
  int wm = wave >> 2, wn = wave & 3;
  int l15 = lane & 15, q = lane >> 4;

  const unsigned short* abase = A0T + (size_t)gl * 64 * NC0 * 64 + (size_t)mt * 128 * 64;
  const unsigned short* bbase = xT  + (size_t)gl * 64 * HD  * 64 + (size_t)nt * 128 * 64;

  fx4 acc[4][2];
  #pragma unroll
  for (int i = 0; i < 4; ++i)
    #pragma unroll
    for (int j = 0; j < 2; ++j) acc[i][j] = fx4{0.f, 0.f, 0.f, 0.f};

  int srow = lane >> 3;                 // 0..7 row within 8-row group
  int sg   = (lane & 7) ^ srow;         // swizzled 16B granule
  size_t soff = (size_t)srow * 64 + (size_t)sg * 8;   // shorts (row stride now 64)

  // prologue: stage chunk 0 into buf 0 (wave w stages rows w*16..+15 of both arrays)
  #pragma unroll
  for (int i = 0; i < 2; ++i) {
    int r0 = wave * 16 + i * 8;
    ASYNC_COPY16(abase + (size_t)r0 * 64 + soff, &a_s[0][r0 * 64]);
    ASYNC_COPY16(bbase + (size_t)r0 * 64 + soff, &b_s[0][r0 * 64]);
  }
  __syncthreads();

  for (int t = 0; t < NPG / 64; ++t) {
    int buf = t & 1;
    if (t < NPG / 64 - 1) {   // issue next chunk into other buffer; drains at the barrier
      size_t co = (size_t)(t + 1) * NC0 * 64;   // NC0*64 == HD*64 == 16384 shorts/chunk
      #pragma unroll
      for (int i = 0; i < 2; ++i) {
        int r0 = wave * 16 + i * 8;
        ASYNC_COPY16(abase + co + (size_t)r0 * 64 + soff, &a_s[buf ^ 1][r0 * 64]);
        ASYNC_COPY16(bbase + co + (size_t)r0 * 64 + soff, &b_s[buf ^ 1][r0 * 64]);
      }
    }
    #pragma unroll
    for (int ks = 0; ks < 2; ++ks) {
      int gx = ((ks * 4 + q) ^ (l15 & 7)) << 3;   // swizzled granule offset (shorts)
      bfx8 af[4], bf[2];
      #pragma unroll
      for (int mi = 0; mi < 4; ++mi)
        af[mi] = *(const bfx8*)&a_s[buf][(wm * 64 + mi * 16 + l15) * 64 + gx];
      #pragma unroll
      for (int ni = 0; ni < 2; ++ni)
        bf[ni] = *(const bfx8*)&b_s[buf][(wn * 32 + ni * 16 + l15) * 64 + gx];
      #pragma unroll
      for (int ni = 0; ni < 2; ++ni)
        #pragma unroll
        for (int mi = 0; mi < 4; ++mi)
          acc[mi][ni] = __builtin_amdgcn_mfma_f32_16x16x32_bf16(af[mi], bf[ni], acc[mi][ni], 0, 0, 0);
    }
    __syncthreads();
  }

  float* dst = f0 + ((size_t)(g0 + gl) * NC0 + (size_t)mt * 128) * HD + (size_t)nt * 128;
  #pragma unroll
  for (int mi = 0; mi < 4; ++mi)
    #pragma unroll
    for (int ni = 0; ni < 2; ++ni) {
      int c = wm * 64 + mi * 16 + q * 4;
      int h = wn * 32 + ni * 16 + l15;
      #pragma unroll
      for (int r = 0; r < 4; ++r)
        dst[(size_t)(c + r) * HD + h] = acc[mi][ni][r];
    }
}

// ---------------- K3: A1 = softmax(f0 @ W1 + b1); W1 staged in LDS (unchanged) ----------------
__global__ __launch_bounds__(256) void k_assign1(
    const float* __restrict__ f0, const float* __restrict__ W1,
    const float* __restrict__ b1, float* __restrict__ A1) {
  __shared__ float w1s[256 * 64];   // 64 KB
  int tid = threadIdx.x;
  #pragma unroll
  for (int i = 0; i < 16; ++i) {
    int off = i * 1024 + tid * 4;
    *(float4*)(w1s + off) = *(const float4*)(W1 + off);
  }
  __syncthreads();
  int lane = tid & 63;
  int rbase = blockIdx.x * 32 + (tid >> 6) * 8;
  float bias = b1[lane];
  for (int rr = 0; rr < 8; ++rr) {
    int row = rbase + rr;
    const float* fr = f0 + (size_t)row * 256;
    float acc = bias;
    for (int k = 0; k < 256; k += 4) {
      float4 fv = *(const float4*)(fr + k);
      acc += fv.x * w1s[(k    ) * 64 + lane];
      acc += fv.y * w1s[(k + 1) * 64 + lane];
      acc += fv.z * w1s[(k + 2) * 64 + lane];
      acc += fv.w * w1s[(k + 3) * 64 + lane];
    }
    float m = acc;
    #pragma unroll
    for (int off = 1; off < 64; off <<= 1) m = fmaxf(m, __shfl_xor(m, off));
    float e = __expf(acc - m);
    float s = e;
    #pragma unroll
    for (int off = 1; off < 64; off <<= 1) s += __shfl_xor(s, off);
    A1[(size_t)row * 64 + lane] = e / s;
  }
}

// ---------------- K4: f1[b][c*256+h] = sum_c0 A1[b][c0][c] * f0[b][c0][h] (unchanged) ----------------
__global__ __launch_bounds__(256) void k_pool1(
    const float* __restrict__ A1, const float* __restrict__ f0, float* __restrict__ f1) {
  int b = blockIdx.x >> 2, cg = blockIdx.x & 3;
  int h = threadIdx.x;
  const float* a1p = A1 + (size_t)b * NC0 * NC1 + cg * 16;
  const float* f0p = f0 + (size_t)b * NC0 * HD + h;
  float acc[16];
  #pragma unroll
  for (int j = 0; j < 16; ++j) acc[j] = 0.f;
  for (int c0 = 0; c0 < 256; ++c0) {
    float fv = f0p[(size_t)c0 * 256];
    #pragma unroll
    for (int j = 0; j < 16; ++j) acc[j] += a1p[c0 * 64 + j] * fv;
  }
  float* d = f1 + (size_t)b * 16384 + (size_t)(cg * 16) * 256 + h;
  #pragma unroll
  for (int j = 0; j < 16; ++j) d[(size_t)j * 256] = acc[j];
}

// ---------------- K5a: ot[b][h] += f1[b][ks*256..+256] . Wf[ks*256..][h] (unchanged) ----------------
__global__ __launch_bounds__(512) void k_final_partial(
    const float* __restrict__ f1, const float* __restrict__ Wf, float* __restrict__ ot) {
  __shared__ float f1s[64 * 256];   // 64 KB: f1[all b][k-slice]
  int ht = blockIdx.x & 3;          // h-tile 0..3
  int ks = blockIdx.x >> 2;         // k-slice 0..63
  int tid = threadIdx.x;
  {
    int b = tid >> 3, c0 = (tid & 7) * 4;
    const float* s = f1 + (size_t)b * 16384 + (size_t)ks * 256 + c0;
    float* d = f1s + b * 256 + c0;
    #pragma unroll
    for (int i = 0; i < 8; ++i) *(float4*)(d + i * 32) = *(const float4*)(s + i * 32);
  }
  __syncthreads();
  int h = ht * 64 + (tid & 63);
  int b0 = (tid >> 6) * 8;          // wave's 8 graphs
  const float* wp = Wf + (size_t)ks * 256 * 256 + h;
  float acc[8];
  #pragma unroll
  for (int j = 0; j < 8; ++j) acc[j] = 0.f;
  for (int k = 0; k < 256; k += 4) {
    float w0 = wp[(size_t)(k    ) * 256];
    float w1 = wp[(size_t)(k + 1) * 256];
    float w2 = wp[(size_t)(k + 2) * 256];
    float w3 = wp[(size_t)(k + 3) * 256];
    #pragma unroll
    for (int j = 0; j < 8; ++j) {
      float4 fv = *(const float4*)(f1s + (b0 + j) * 256 + k);
      acc[j] += fv.x * w0 + fv.y * w1 + fv.z * w2 + fv.w * w3;
    }
  }
  #pragma unroll
  for (int j = 0; j < 8; ++j) atomicAdd(&ot[(b0 + j) * 256 + h], acc[j]);
}

// ---------------- K5b: out = relu(ot + bf) (unchanged) ----------------
__global__ __launch_bounds__(256) void k_final_out(
    const float* __restrict__ ot, const float* __restrict__ bfv, float* __restrict__ out) {
  int i = blockIdx.x * 256 + threadIdx.x;
  float v = ot[i] + bfv[i & 255];
  out[i] = v > 0.f ? v : 0.f;
}

extern "C" void kernel_launch(void* const* d_in, const int* in_sizes, int n_in,
                              void* d_out, int out_size, void* d_ws, size_t ws_size,
                              hipStream_t stream) {
  const float* x   = (const float*)d_in[0];
  const float* W0  = (const float*)d_in[3];
  const float* b0  = (const float*)d_in[4];
  const float* W1  = (const float*)d_in[5];
  const float* b1  = (const float*)d_in[6];
  const float* Wf  = (const float*)d_in[7];
  const float* bfv = (const float*)d_in[8];
  float* out = (float*)d_out;
  char* ws = (char*)d_ws;

  // layout: f0 16 MB @0; ot @32M; W0F @32M+64K;
  // chunk region @32M+192K: xT (G*2MB) + A0T (G*2MB). f1 aliases xT, A1 aliases A0T.
  float* f0  = (float*)ws;
  float* ot  = (float*)(ws + ((size_t)32 << 20));
  unsigned short* W0F = (unsigned short*)(ws + ((size_t)32 << 20) + 65536);
  size_t chunk_off = ((size_t)32 << 20) + 65536 + 131072;
  size_t per_graph = (size_t)4 * HD * NPG;   // xT(2MB)+A0T(2MB)
  size_t avail = ws_size > chunk_off ? ws_size - chunk_off : 0;
  int G = (int)(avail / per_graph);
  if (G > 64) G = 64;
  if (G < 1) G = 1;
  unsigned short* xT  = (unsigned short*)(ws + chunk_off);
  unsigned short* A0T = xT + (size_t)G * HD * NPG;
  float* f1 = (float*)xT;    // 16 MB, used after k_pool0 (needs G>=8; ws floor gives G=64)
  float* A1 = (float*)A0T;   // 4 MB, used after k_pool0

  hipMemsetAsync(ot, 0, 65536, stream);
  k_w0f<<<32, 256, 0, stream>>>(W0, W0F);

  for (int g0 = 0; g0 < NG; g0 += G) {
    int gc = (NG - g0 < G) ? (NG - g0) : G;
    k_assign0<<<gc * 64, 256, 0, stream>>>(x, W0F, b0, A0T, xT, g0);
    k_pool0<<<gc * 4, 512, 0, stream>>>(A0T, xT, f0, g0);
  }
  k_assign1<<<512, 256, 0, stream>>>(f0, W1, b1, A1);
  k_pool1<<<256, 256, 0, stream>>>(A1, f0, f1);
  k_final_partial<<<256, 512, 0, stream>>>(f1, Wf, ot);
  k_final_out<<<64, 256, 0, stream>>>(ot, bfv, out);
}